// Round 3
// baseline (530.700 us; speedup 1.0000x reference)
//
#include <hip/hip_runtime.h>
#include <stdint.h>

#define VV 128000
#define BLOCK 1024
#define NB 4096

typedef unsigned long long ull;

__device__ __forceinline__ uint32_t rotl32(uint32_t x, int r){ return (x << r) | (x >> (32 - r)); }

// Bit-exact replica of jax.random.exponential(key(42), (256,128000), f32) at flat
// index f, under jax_threefry_partitionable=True (default in modern JAX):
// per element, threefry2x32(key, counter=(hi32(i), lo32(i))), bits = out0 ^ out1.
__device__ __forceinline__ float exp_noise(uint32_t f){
  const uint32_t ks0 = 0u, ks1 = 42u, ks2 = 0x1BD11BDAu ^ 0u ^ 42u;
  uint32_t x0 = 0u + ks0;   // counter hi word (indices < 2^32 -> 0)
  uint32_t x1 = f + ks1;    // counter lo word
#define R1(r) { x0 += x1; x1 = rotl32(x1, r); x1 ^= x0; }
  R1(13) R1(15) R1(26) R1(6)   x0 += ks1; x1 += ks2 + 1u;
  R1(17) R1(29) R1(16) R1(24)  x0 += ks2; x1 += ks0 + 2u;
  R1(13) R1(15) R1(26) R1(6)   x0 += ks0; x1 += ks1 + 3u;
  R1(17) R1(29) R1(16) R1(24)  x0 += ks1; x1 += ks2 + 4u;
  R1(13) R1(15) R1(26) R1(6)   x0 += ks2; x1 += ks0 + 5u;
#undef R1
  uint32_t bits = x0 ^ x1;
  float u = __uint_as_float((bits >> 9) | 0x3F800000u) - 1.0f;
  float e = -log1pf(-u);
  return fmaxf(e, 1e-10f);
}

// ascending-order key: larger float -> larger key (total order; no NaN in input)
__device__ __forceinline__ uint32_t fkey(float x){
  uint32_t u = __float_as_uint(x);
  return u ^ ((u & 0x80000000u) ? 0xFFFFFFFFu : 0x80000000u);
}
__device__ __forceinline__ float keyval(uint32_t k){
  uint32_t bits = (k & 0x80000000u) ? (k ^ 0x80000000u) : ~k;
  return __uint_as_float(bits);
}

// In-place inclusive suffix sum over NB=4096 entries (4 per thread + Hillis-Steele).
__device__ void suffix_scan_u(uint32_t* h, uint32_t* tmp, int tid){
  const int base = tid * 4;
  uint32_t l0=h[base], l1=h[base+1], l2=h[base+2], l3=h[base+3];
  uint32_t s3=l3, s2=l2+s3, s1=l1+s2, s0=l0+s1;
  tmp[tid] = s0; __syncthreads();
  for (int d=1; d<BLOCK; d<<=1){
    uint32_t add = (tid+d<BLOCK) ? tmp[tid+d] : 0u;
    __syncthreads();
    tmp[tid] += add;
    __syncthreads();
  }
  uint32_t E = (tid+1<BLOCK) ? tmp[tid+1] : 0u;
  h[base]=s0+E; h[base+1]=s1+E; h[base+2]=s2+E; h[base+3]=s3+E;
  __syncthreads();
}
__device__ void suffix_scan_f(float* h, float* tmp, int tid){
  const int base = tid * 4;
  float l0=h[base], l1=h[base+1], l2=h[base+2], l3=h[base+3];
  float s3=l3, s2=l2+s3, s1=l1+s2, s0=l0+s1;
  tmp[tid] = s0; __syncthreads();
  for (int d=1; d<BLOCK; d<<=1){
    float add = (tid+d<BLOCK) ? tmp[tid+d] : 0.f;
    __syncthreads();
    tmp[tid] += add;
    __syncthreads();
  }
  float E = (tid+1<BLOCK) ? tmp[tid+1] : 0.f;
  h[base]=s0+E; h[base+1]=s1+E; h[base+2]=s2+E; h[base+3]=s3+E;
  __syncthreads();
}

// tid0-serial: move the t smallest of a[0..n) to front, return t-th smallest.
__device__ uint32_t select_tth_smallest(uint32_t* a, int n, int t){
  for (int i=0;i<t;i++){
    int mi=i; uint32_t mv=a[i];
    for (int j=i+1;j<n;j++) if (a[j]<mv){ mv=a[j]; mi=j; }
    a[mi]=a[i]; a[i]=mv;
  }
  return a[t-1];
}

#define ROW_LOOP_BEGIN \
    for (int c=tid; c<VV/4; c+=BLOCK){ \
      float4 x4 = reinterpret_cast<const float4*>(row)[c]; \
      float xs[4] = {x4.x, x4.y, x4.z, x4.w}; \
      int v = c*4; \
      _Pragma("unroll") \
      for (int j=0;j<4;j++){ \
        float x = xs[j]/T; \
        uint32_t u = fkey(x); \
        uint32_t idx = (uint32_t)(v+j); \
        (void)idx;
#define ROW_LOOP_END } }

__global__ __launch_bounds__(BLOCK) void sampler_kernel(
    const float* __restrict__ logits, const float* __restrict__ temps,
    const int* __restrict__ topks, const float* __restrict__ topps,
    int* __restrict__ out)
{
  __shared__ float    S[NB];      // phase-1 mass suffix (persistent)
  __shared__ float    wf[NB];     // work masses
  __shared__ uint32_t wu[NB];     // work counts / gather list
  __shared__ float    tmpf[BLOCK];
  __shared__ uint32_t tmpu[BLOCK];
  __shared__ ull      red[BLOCK];
  __shared__ int s_idx, s_n, s_tk, s_ntk, s_tp, s_ntp;
  __shared__ uint32_t s_uk, s_idxk, s_up, s_idxp;
  __shared__ float s_m, s_Zk;

  const int b   = blockIdx.x;
  const int tid = threadIdx.x;
  const float T = temps[b];
  const int   k = topks[b];
  const float p = topps[b];
  const float* row = logits + (size_t)b * VV;
  const bool topk_act = (k > 0) && (k < VV);
  const bool topp_act = (p > 0.0f) && (p < 1.0f);

  // ================= phase 1: max + 12-bit count & mass histograms =================
  for (int i=tid;i<NB;i+=BLOCK){ S[i]=0.f; wu[i]=0u; }
  __syncthreads();
  float lmax = -3.4e38f;
  ROW_LOOP_BEGIN
    lmax = fmaxf(lmax, x);
    atomicAdd(&wu[u>>20], 1u);
    atomicAdd(&S[u>>20], expf(x));
  ROW_LOOP_END
  tmpf[tid] = lmax; __syncthreads();
  for (int d=BLOCK/2; d>0; d>>=1){
    if (tid < d) tmpf[tid] = fmaxf(tmpf[tid], tmpf[tid+d]);
    __syncthreads();
  }
  if (tid==0) s_m = tmpf[0];
  __syncthreads();
  suffix_scan_u(wu, tmpu, tid);   // wu[i] = count of items with bucket >= i (exact ints)
  suffix_scan_f(S,  tmpf, tid);   // S[i]  = mass  of items with bucket >= i

  // ================= top-k threshold (integer-exact) =================
  uint32_t uk = 0u, idxk = 0xFFFFFFFFu;
  int bk1 = -1;
  if (topk_act){
    // L1: bucket containing the k-th largest
    if (tid==0) s_idx = 0;
    __syncthreads();
    for (int i=tid;i<NB;i+=BLOCK){
      uint32_t a  = wu[i];
      uint32_t nn = (i+1<NB) ? wu[i+1] : 0u;
      if (a >= (uint32_t)k && nn < (uint32_t)k) s_idx = i;
    }
    __syncthreads();
    bk1 = s_idx;
    const uint32_t c_above1 = (bk1+1<NB) ? wu[bk1+1] : 0u;
    const float    M_above1 = (bk1+1<NB) ? S[bk1+1]  : 0.f;
    __syncthreads();
    // L2: 12-bit refinement within bucket bk1
    for (int i=tid;i<NB;i+=BLOCK){ wu[i]=0u; wf[i]=0.f; }
    __syncthreads();
    ROW_LOOP_BEGIN
      if ((int)(u>>20) == bk1){
        atomicAdd(&wu[(u>>8)&0xFFFu], 1u);
        atomicAdd(&wf[(u>>8)&0xFFFu], expf(x));
      }
    ROW_LOOP_END
    __syncthreads();
    suffix_scan_u(wu, tmpu, tid);
    suffix_scan_f(wf, tmpf, tid);
    if (tid==0) s_idx = 0;
    __syncthreads();
    for (int i=tid;i<NB;i+=BLOCK){
      uint32_t a  = c_above1 + wu[i];
      uint32_t nn = c_above1 + ((i+1<NB) ? wu[i+1] : 0u);
      if (a >= (uint32_t)k && nn < (uint32_t)k) s_idx = i;
    }
    __syncthreads();
    const int bk2 = s_idx;
    const uint32_t c_above2 = c_above1 + ((bk2+1<NB) ? wu[bk2+1] : 0u);
    const float    M_above2 = M_above1 + ((bk2+1<NB) ? wf[bk2+1] : 0.f);
    __syncthreads();
    // L3: 8-bit refinement -> exact 32-bit key of k-th largest
    if (tid < 256){ wu[tid]=0u; wf[tid]=0.f; }
    __syncthreads();
    const uint32_t top24k = (((uint32_t)bk1)<<12) | (uint32_t)bk2;
    ROW_LOOP_BEGIN
      if ((u>>8) == top24k){
        atomicAdd(&wu[u & 0xFFu], 1u);
        atomicAdd(&wf[u & 0xFFu], expf(x));
      }
    ROW_LOOP_END
    __syncthreads();
    if (tid==0){
      uint32_t r = 0u; float mr = 0.f; int b3 = 0;
      for (int i=255;i>=0;--i){
        if (c_above2 + r + wu[i] >= (uint32_t)k){ b3 = i; break; }
        r += wu[i]; mr += wf[i];
      }
      const uint32_t cgt = c_above2 + r;          // exact count of items strictly above u_k
      const float mgt = M_above2 + mr;            // mass strictly above u_k
      const int nt = (int)wu[b3];
      const int tk = k - (int)cgt;                // in [1, nt] by construction
      s_uk  = (((uint32_t)bk1)<<20) | (((uint32_t)bk2)<<8) | (uint32_t)b3;
      s_tk  = tk; s_ntk = nt;
      s_Zk  = mgt + (float)tk * expf(keyval(s_uk));
      s_n   = 0;
    }
    __syncthreads();
    uk = s_uk;
    if (s_tk < s_ntk){
      ROW_LOOP_BEGIN
        if (u == uk){
          int pos = atomicAdd(&s_n, 1);
          if (pos < NB) wu[pos] = idx;
        }
      ROW_LOOP_END
      __syncthreads();
      if (tid==0){
        int n2 = min(s_n, NB);
        int t  = min(s_tk, n2);
        s_idxk = select_tth_smallest(wu, n2, t);
      }
      __syncthreads();
      idxk = s_idxk;
    }
  }
  const float Zk = topk_act ? s_Zk : S[0];

  // ================= top-p threshold (mass-based, restricted to kept-by-k) =================
  uint32_t up = 0u, idxp = 0xFFFFFFFFu;
  const float tgt = p * Zk;
  const bool pall = (!topp_act) || (tgt >= Zk);
  if (!pall){
    // L1: buckets strictly above bk1 are fully kept -> use phase-1 mass suffix S
    if (tid==0) s_idx = -2;
    __syncthreads();
    for (int i=tid;i<NB;i+=BLOCK){
      if (i > bk1){
        float a  = S[i];
        float nn = (i+1<NB) ? S[i+1] : 0.f;
        if (a > tgt && nn <= tgt) s_idx = i;
      }
    }
    __syncthreads();
    int bp1 = (s_idx >= 0) ? s_idx : bk1;   // no crossing above -> boundary inside bk1
    if (bp1 < 0) bp1 = 0;                    // defensive (unreachable)
    const float Mab = (bp1+1<NB) ? S[bp1+1] : 0.f;
    __syncthreads();
    // L2: masses of kept items within bucket bp1
    for (int i=tid;i<NB;i+=BLOCK) wf[i]=0.f;
    __syncthreads();
    ROW_LOOP_BEGIN
      if ((int)(u>>20) == bp1){
        bool kk_ok = (!topk_act) || (u > uk) || (u == uk && idx <= idxk);
        if (kk_ok) atomicAdd(&wf[(u>>8)&0xFFFu], expf(x));
      }
    ROW_LOOP_END
    __syncthreads();
    suffix_scan_f(wf, tmpf, tid);
    if (tid==0) s_idx = -2;
    __syncthreads();
    for (int i=tid;i<NB;i+=BLOCK){
      float a  = Mab + wf[i];
      float nn = Mab + ((i+1<NB) ? wf[i+1] : 0.f);
      if (a > tgt && nn <= tgt) s_idx = i;
    }
    __syncthreads();
    int bp2;
    if (s_idx >= 0){ bp2 = s_idx; }
    else {
      // fp-wobble fallback: lowest nonempty sub-bucket
      if (tid==0) s_idx = NB;
      __syncthreads();
      for (int i=tid;i<NB;i+=BLOCK){
        float a  = wf[i];
        float nn = (i+1<NB) ? wf[i+1] : 0.f;
        if (a > nn) atomicMin(&s_idx, i);
      }
      __syncthreads();
      bp2 = (s_idx < NB) ? s_idx : 0;
    }
    const float Mab2 = Mab + ((bp2+1<NB) ? wf[bp2+1] : 0.f);
    __syncthreads();
    // L3
    if (tid < 256){ wf[tid]=0.f; wu[tid]=0u; }
    __syncthreads();
    const uint32_t top24p = (((uint32_t)bp1)<<12) | (uint32_t)bp2;
    ROW_LOOP_BEGIN
      if ((u>>8) == top24p){
        bool kk_ok = (!topk_act) || (u > uk) || (u == uk && idx <= idxk);
        if (kk_ok){
          atomicAdd(&wf[u & 0xFFu], expf(x));
          atomicAdd(&wu[u & 0xFFu], 1u);
        }
      }
    ROW_LOOP_END
    __syncthreads();
    if (tid==0){
      float run = 0.f; int b3 = -1; float mgt = 0.f;
      for (int i=255;i>=0;--i){
        float sufn = run; run += wf[i];
        if (Mab2 + run > tgt && Mab2 + sufn <= tgt){ b3 = i; mgt = Mab2 + sufn; break; }
      }
      if (b3 < 0){
        float run2 = 0.f;
        for (int i=255;i>=0;--i){
          if (wu[i] > 0u){ b3 = i; mgt = Mab2 + run2; }
          run2 += wf[i];
        }
        if (b3 < 0){ b3 = 0; mgt = Mab2; }
      }
      const uint32_t upv = (((uint32_t)bp1)<<20) | (((uint32_t)bp2)<<8) | (uint32_t)b3;
      const int ntp = (int)wu[b3];
      const float ev = expf(keyval(upv));
      int t = 0;
      for (int j=1;j<=ntp;j++){
        float before = mgt + (float)(j-1) * ev;
        if (before / Zk <= p) t++; else break;
      }
      if (t < 1) t = 1;
      s_up = upv; s_tp = t; s_ntp = ntp; s_n = 0;
    }
    __syncthreads();
    up = s_up;
    if (s_tp < s_ntp){
      ROW_LOOP_BEGIN
        if (u == up){
          bool kk_ok = (!topk_act) || (u > uk) || (u == uk && idx <= idxk);
          if (kk_ok){
            int pos = atomicAdd(&s_n, 1);
            if (pos < NB) wu[pos] = idx;
          }
        }
      ROW_LOOP_END
      __syncthreads();
      if (tid==0){
        int n2 = min(s_n, NB);
        int t  = min(s_tp, n2);
        s_idxp = select_tth_smallest(wu, n2, t);
      }
      __syncthreads();
      idxp = s_idxp;
    }
  }

  // ================= final: argmax over kept set of (exp(x-m)/Zs)/e =================
  const float m  = s_m;
  const float Zs = Zk * expf(-m);   // positive row-constant; argmax-invariant scale
  ull best = 0ull;
  ROW_LOOP_BEGIN
    bool kk_ok = (!topk_act) || (u > uk) || (u == uk && idx <= idxk);
    bool kp_ok = pall || (u > up) || (u == up && idx <= idxp);
    if (kk_ok && kp_ok){
      float q = (expf(x - m) / Zs) / exp_noise((uint32_t)b * (uint32_t)VV + idx);
      ull pk = (((ull)__float_as_uint(q)) << 32) | (uint32_t)(~idx);
      best = (pk > best) ? pk : best;
    }
  ROW_LOOP_END
  red[tid] = best; __syncthreads();
  for (int d=BLOCK/2; d>0; d>>=1){
    if (tid < d){ ull o = red[tid+d]; if (o > red[tid]) red[tid] = o; }
    __syncthreads();
  }
  if (tid==0) out[b] = (int)(~(uint32_t)(red[0] & 0xFFFFFFFFull));
}

extern "C" void kernel_launch(void* const* d_in, const int* in_sizes, int n_in,
                              void* d_out, int out_size, void* d_ws, size_t ws_size,
                              hipStream_t stream) {
  (void)in_sizes; (void)n_in; (void)out_size; (void)d_ws; (void)ws_size;
  const float* logits = (const float*)d_in[0];
  const float* temps  = (const float*)d_in[1];
  const int*   ks     = (const int*)d_in[2];
  const float* ps     = (const float*)d_in[3];
  int* out = (int*)d_out;
  sampler_kernel<<<256, BLOCK, 0, stream>>>(logits, temps, ks, ps, out);
}

// Round 4
// 247.309 us; speedup vs baseline: 2.1459x; 2.1459x over previous
//
#include <hip/hip_runtime.h>
#include <stdint.h>

#define VV 128000
#define BLOCK 1024
#define NB 4096
#define CAP 4096

typedef unsigned long long ull;

__device__ __forceinline__ uint32_t rotl32(uint32_t x, int r){ return (x << r) | (x >> (32 - r)); }

// Bit-exact replica of jax.random.exponential(key(42), (256,128000), f32) at flat
// index f, under jax_threefry_partitionable=True (default in modern JAX):
// per element, threefry2x32(key, counter=(hi32(i), lo32(i))), bits = out0 ^ out1.
__device__ __forceinline__ float exp_noise(uint32_t f){
  const uint32_t ks0 = 0u, ks1 = 42u, ks2 = 0x1BD11BDAu ^ 0u ^ 42u;
  uint32_t x0 = 0u + ks0;   // counter hi word
  uint32_t x1 = f + ks1;    // counter lo word
#define R1(r) { x0 += x1; x1 = rotl32(x1, r); x1 ^= x0; }
  R1(13) R1(15) R1(26) R1(6)   x0 += ks1; x1 += ks2 + 1u;
  R1(17) R1(29) R1(16) R1(24)  x0 += ks2; x1 += ks0 + 2u;
  R1(13) R1(15) R1(26) R1(6)   x0 += ks0; x1 += ks1 + 3u;
  R1(17) R1(29) R1(16) R1(24)  x0 += ks1; x1 += ks2 + 4u;
  R1(13) R1(15) R1(26) R1(6)   x0 += ks2; x1 += ks0 + 5u;
#undef R1
  uint32_t bits = x0 ^ x1;
  float u = __uint_as_float((bits >> 9) | 0x3F800000u) - 1.0f;
  float e = -log1pf(-u);
  return fmaxf(e, 1e-10f);
}

// ascending-order key: larger float -> larger key (total order; no NaN in input)
__device__ __forceinline__ uint32_t fkey(float x){
  uint32_t u = __float_as_uint(x);
  return u ^ ((u & 0x80000000u) ? 0xFFFFFFFFu : 0x80000000u);
}
__device__ __forceinline__ float keyval(uint32_t k){
  uint32_t bits = (k & 0x80000000u) ? (k ^ 0x80000000u) : ~k;
  return __uint_as_float(bits);
}

// In-place inclusive suffix sum over NB=4096 entries (4 per thread + Hillis-Steele).
__device__ void suffix_scan_u(uint32_t* h, uint32_t* tmp, int tid){
  const int base = tid * 4;
  uint32_t l0=h[base], l1=h[base+1], l2=h[base+2], l3=h[base+3];
  uint32_t s3=l3, s2=l2+s3, s1=l1+s2, s0=l0+s1;
  tmp[tid] = s0; __syncthreads();
  for (int d=1; d<BLOCK; d<<=1){
    uint32_t add = (tid+d<BLOCK) ? tmp[tid+d] : 0u;
    __syncthreads();
    tmp[tid] += add;
    __syncthreads();
  }
  uint32_t E = (tid+1<BLOCK) ? tmp[tid+1] : 0u;
  h[base]=s0+E; h[base+1]=s1+E; h[base+2]=s2+E; h[base+3]=s3+E;
  __syncthreads();
}
__device__ void suffix_scan_f(float* h, float* tmp, int tid){
  const int base = tid * 4;
  float l0=h[base], l1=h[base+1], l2=h[base+2], l3=h[base+3];
  float s3=l3, s2=l2+s3, s1=l1+s2, s0=l0+s1;
  tmp[tid] = s0; __syncthreads();
  for (int d=1; d<BLOCK; d<<=1){
    float add = (tid+d<BLOCK) ? tmp[tid+d] : 0.f;
    __syncthreads();
    tmp[tid] += add;
    __syncthreads();
  }
  float E = (tid+1<BLOCK) ? tmp[tid+1] : 0.f;
  h[base]=s0+E; h[base+1]=s1+E; h[base+2]=s2+E; h[base+3]=s3+E;
  __syncthreads();
}

// tid0-serial: move the t smallest of a[0..n) to front, return t-th smallest.
__device__ uint32_t select_tth_smallest(uint32_t* a, int n, int t){
  for (int i=0;i<t;i++){
    int mi=i; uint32_t mv=a[i];
    for (int j=i+1;j<n;j++) if (a[j]<mv){ mv=a[j]; mi=j; }
    a[mi]=a[i]; a[i]=mv;
  }
  return a[t-1];
}

// 4-wide unrolled row loop: 4 independent dwordx4 loads issued up front (latency hiding).
#define ROW4_BEGIN \
    for (int c0 = tid; c0 < VV/4; c0 += BLOCK*4){ \
      float4 qv[4]; int cb[4]; bool gv[4]; \
      _Pragma("unroll") \
      for (int t=0;t<4;t++){ int cc = c0 + t*BLOCK; gv[t] = (cc < VV/4); cb[t] = cc*4; if (gv[t]) qv[t] = rp[cc]; } \
      _Pragma("unroll") \
      for (int t=0;t<4;t++) if (gv[t]){ \
        float xs[4] = {qv[t].x, qv[t].y, qv[t].z, qv[t].w}; \
        _Pragma("unroll") \
        for (int j=0;j<4;j++){ \
          float x = xs[j]/T; \
          uint32_t u = fkey(x); \
          uint32_t idx = (uint32_t)(cb[t]+j); \
          (void)idx;
#define ROW4_END } } }

__global__ __launch_bounds__(BLOCK) void sampler_kernel(
    const float* __restrict__ logits, const float* __restrict__ temps,
    const int* __restrict__ topks, const float* __restrict__ topps,
    int* __restrict__ out)
{
  __shared__ uint32_t wu[NB];       // counts / gather scratch (16 KB)
  __shared__ ull      cand[CAP];    // fast-path candidates (32 KB); slow path aliases S/wf here
  __shared__ float    tmpf[BLOCK];
  __shared__ uint32_t tmpu[BLOCK];
  __shared__ float    ck[BLOCK];
  __shared__ ull      red[BLOCK];
  __shared__ int s_idx, s_n, s_tk, s_ntk, s_tp, s_ntp, s_cnt;
  __shared__ uint32_t s_uk, s_idxk, s_up, s_idxp;
  __shared__ float s_m, s_Zk, s_Ztot;

  float* S  = (float*)cand;         // [NB] slow-path mass suffix
  float* wf = ((float*)cand) + NB;  // [NB] slow-path work masses

  const int b   = blockIdx.x;
  const int tid = threadIdx.x;
  const float T = temps[b];
  const int   k = topks[b];
  const float p = topps[b];
  const float* row = logits + (size_t)b * VV;
  const float4* rp = reinterpret_cast<const float4*>(row);
  const bool topk_act = (k > 0) && (k < VV);
  const bool topp_act = (p > 0.0f) && (p < 1.0f);

  // ============================================================================
  // FAST PATH (k in [1,1023]): counts histogram -> gather top candidates -> LDS sort
  // ============================================================================
  if (topk_act){
    for (int i=tid;i<NB;i+=BLOCK) wu[i]=0u;
    __syncthreads();
    ROW4_BEGIN
      atomicAdd(&wu[u>>20], 1u);
    ROW4_END
    __syncthreads();
    suffix_scan_u(wu, tmpu, tid);   // wu[i] = count of items with bucket >= i
    if (tid==0) s_idx = 0;
    __syncthreads();
    for (int i=tid;i<NB;i+=BLOCK){
      uint32_t a  = wu[i];
      uint32_t nn = (i+1<NB) ? wu[i+1] : 0u;
      if (a >= (uint32_t)k && nn < (uint32_t)k) s_idx = i;
    }
    __syncthreads();
    const uint32_t beta = (uint32_t)s_idx;
    const int n = (int)wu[beta];    // exact candidate count, >= k
    if (n <= CAP){
      if (tid==0) s_n = 0;
      __syncthreads();
      ROW4_BEGIN
        if ((u>>20) >= beta){
          int pos = atomicAdd(&s_n, 1);
          cand[pos] = (((ull)(~u))<<32) | idx;   // pos < n <= CAP guaranteed
        }
      ROW4_END
      __syncthreads();
      int N = 2; while (N < n) N <<= 1;
      for (int i=tid;i<N;i+=BLOCK) if (i >= n) cand[i] = 0xFFFFFFFFFFFFFFFFull;
      __syncthreads();
      // bitonic ascending on packed (~key, idx): value desc, idx asc = stable argsort(-x)
      for (int len=2; len<=N; len<<=1){
        for (int j=len>>1; j>0; j>>=1){
          for (int i=tid; i<N; i+=BLOCK){
            int l = i ^ j;
            if (l > i){
              ull a = cand[i], c2 = cand[l];
              bool asc = ((i & len) == 0);
              if (asc ? (a > c2) : (a < c2)){ cand[i]=c2; cand[l]=a; }
            }
          }
          __syncthreads();
        }
      }
      // exact top-k = first k entries. Softmax over them.
      const int kk = k;                       // k <= n
      const float m = keyval(~(uint32_t)(cand[0]>>32));
      float w = 0.f; uint32_t myidx = 0u;
      if (tid < kk){
        ull e = cand[tid];
        myidx = (uint32_t)e;
        w = expf(keyval(~(uint32_t)(e>>32)) - m);
      }
      // Zk = sum of weights (tree reduction)
      ck[tid] = w; __syncthreads();
      for (int d=BLOCK/2; d>0; d>>=1){
        if (tid < d) ck[tid] += ck[tid+d];
        __syncthreads();
      }
      if (tid==0) s_Ztot = ck[0];
      __syncthreads();
      const float Zk = s_Ztot;
      // cumsum of probs (inclusive scan), count cumsum <= p among first kk
      ck[tid] = w / Zk; __syncthreads();
      for (int d=1; d<BLOCK; d<<=1){
        float add = (tid >= d) ? ck[tid-d] : 0.f;
        __syncthreads();
        ck[tid] += add;
        __syncthreads();
      }
      if (tid==0) s_cnt = 0;
      tmpu[tid] = (tid < kk && ck[tid] <= p) ? 1u : 0u;
      __syncthreads();
      for (int d=BLOCK/2; d>0; d>>=1){
        if (tid < d) tmpu[tid] += tmpu[tid+d];
        __syncthreads();
      }
      int L;
      if (!topp_act) L = kk;
      else { int c = (int)tmpu[0]; L = (c >= kk) ? kk : (c + 1); }
      // Gumbel-race argmax over first L entries: argmax w_i / e_i (scale-invariant)
      ull best = 0ull;
      if (tid < L){
        float q = w / exp_noise((uint32_t)b * (uint32_t)VV + myidx);
        best = (((ull)__float_as_uint(q)) << 32) | (uint32_t)(~myidx);
      }
      red[tid] = best; __syncthreads();
      for (int d=BLOCK/2; d>0; d>>=1){
        if (tid < d){ ull o = red[tid+d]; if (o > red[tid]) red[tid] = o; }
        __syncthreads();
      }
      if (tid==0) out[b] = (int)(~(uint32_t)(red[0] & 0xFFFFFFFFull));
      return;
    }
    __syncthreads();  // fallback: n > CAP (statistically never) -> full radix path below
  }

  // ============================================================================
  // SLOW PATH (k==0, or fast-path overflow): round-3 verified radix machinery
  // ============================================================================
  // phase 1: max + 12-bit count & mass histograms
  for (int i=tid;i<NB;i+=BLOCK){ S[i]=0.f; wu[i]=0u; }
  __syncthreads();
  float lmax = -3.4e38f;
  ROW4_BEGIN
    lmax = fmaxf(lmax, x);
    atomicAdd(&wu[u>>20], 1u);
    atomicAdd(&S[u>>20], expf(x));
  ROW4_END
  tmpf[tid] = lmax; __syncthreads();
  for (int d=BLOCK/2; d>0; d>>=1){
    if (tid < d) tmpf[tid] = fmaxf(tmpf[tid], tmpf[tid+d]);
    __syncthreads();
  }
  if (tid==0) s_m = tmpf[0];
  __syncthreads();
  suffix_scan_u(wu, tmpu, tid);
  suffix_scan_f(S,  tmpf, tid);

  // top-k threshold (integer-exact)
  uint32_t uk = 0u, idxk = 0xFFFFFFFFu;
  int bk1 = -1;
  if (topk_act){
    if (tid==0) s_idx = 0;
    __syncthreads();
    for (int i=tid;i<NB;i+=BLOCK){
      uint32_t a  = wu[i];
      uint32_t nn = (i+1<NB) ? wu[i+1] : 0u;
      if (a >= (uint32_t)k && nn < (uint32_t)k) s_idx = i;
    }
    __syncthreads();
    bk1 = s_idx;
    const uint32_t c_above1 = (bk1+1<NB) ? wu[bk1+1] : 0u;
    const float    M_above1 = (bk1+1<NB) ? S[bk1+1]  : 0.f;
    __syncthreads();
    for (int i=tid;i<NB;i+=BLOCK){ wu[i]=0u; wf[i]=0.f; }
    __syncthreads();
    ROW4_BEGIN
      if ((int)(u>>20) == bk1){
        atomicAdd(&wu[(u>>8)&0xFFFu], 1u);
        atomicAdd(&wf[(u>>8)&0xFFFu], expf(x));
      }
    ROW4_END
    __syncthreads();
    suffix_scan_u(wu, tmpu, tid);
    suffix_scan_f(wf, tmpf, tid);
    if (tid==0) s_idx = 0;
    __syncthreads();
    for (int i=tid;i<NB;i+=BLOCK){
      uint32_t a  = c_above1 + wu[i];
      uint32_t nn = c_above1 + ((i+1<NB) ? wu[i+1] : 0u);
      if (a >= (uint32_t)k && nn < (uint32_t)k) s_idx = i;
    }
    __syncthreads();
    const int bk2 = s_idx;
    const uint32_t c_above2 = c_above1 + ((bk2+1<NB) ? wu[bk2+1] : 0u);
    const float    M_above2 = M_above1 + ((bk2+1<NB) ? wf[bk2+1] : 0.f);
    __syncthreads();
    if (tid < 256){ wu[tid]=0u; wf[tid]=0.f; }
    __syncthreads();
    const uint32_t top24k = (((uint32_t)bk1)<<12) | (uint32_t)bk2;
    ROW4_BEGIN
      if ((u>>8) == top24k){
        atomicAdd(&wu[u & 0xFFu], 1u);
        atomicAdd(&wf[u & 0xFFu], expf(x));
      }
    ROW4_END
    __syncthreads();
    if (tid==0){
      uint32_t r = 0u; float mr = 0.f; int b3 = 0;
      for (int i=255;i>=0;--i){
        if (c_above2 + r + wu[i] >= (uint32_t)k){ b3 = i; break; }
        r += wu[i]; mr += wf[i];
      }
      const uint32_t cgt = c_above2 + r;
      const float mgt = M_above2 + mr;
      const int nt = (int)wu[b3];
      const int tk = k - (int)cgt;
      s_uk  = (((uint32_t)bk1)<<20) | (((uint32_t)bk2)<<8) | (uint32_t)b3;
      s_tk  = tk; s_ntk = nt;
      s_Zk  = mgt + (float)tk * expf(keyval(s_uk));
      s_n   = 0;
    }
    __syncthreads();
    uk = s_uk;
    if (s_tk < s_ntk){
      ROW4_BEGIN
        if (u == uk){
          int pos = atomicAdd(&s_n, 1);
          if (pos < NB) wu[pos] = idx;
        }
      ROW4_END
      __syncthreads();
      if (tid==0){
        int n2 = min(s_n, NB);
        int t  = min(s_tk, n2);
        s_idxk = select_tth_smallest(wu, n2, t);
      }
      __syncthreads();
      idxk = s_idxk;
    }
  }
  const float Zk = topk_act ? s_Zk : S[0];

  // top-p threshold (mass-based, restricted to kept-by-k)
  uint32_t up = 0u, idxp = 0xFFFFFFFFu;
  const float tgt = p * Zk;
  const bool pall = (!topp_act) || (tgt >= Zk);
  if (!pall){
    if (tid==0) s_idx = -2;
    __syncthreads();
    for (int i=tid;i<NB;i+=BLOCK){
      if (i > bk1){
        float a  = S[i];
        float nn = (i+1<NB) ? S[i+1] : 0.f;
        if (a > tgt && nn <= tgt) s_idx = i;
      }
    }
    __syncthreads();
    int bp1 = (s_idx >= 0) ? s_idx : bk1;
    if (bp1 < 0) bp1 = 0;
    const float Mab = (bp1+1<NB) ? S[bp1+1] : 0.f;
    __syncthreads();
    for (int i=tid;i<NB;i+=BLOCK) wf[i]=0.f;
    __syncthreads();
    ROW4_BEGIN
      if ((int)(u>>20) == bp1){
        bool kk_ok = (!topk_act) || (u > uk) || (u == uk && idx <= idxk);
        if (kk_ok) atomicAdd(&wf[(u>>8)&0xFFFu], expf(x));
      }
    ROW4_END
    __syncthreads();
    suffix_scan_f(wf, tmpf, tid);
    if (tid==0) s_idx = -2;
    __syncthreads();
    for (int i=tid;i<NB;i+=BLOCK){
      float a  = Mab + wf[i];
      float nn = Mab + ((i+1<NB) ? wf[i+1] : 0.f);
      if (a > tgt && nn <= tgt) s_idx = i;
    }
    __syncthreads();
    int bp2;
    if (s_idx >= 0){ bp2 = s_idx; }
    else {
      if (tid==0) s_idx = NB;
      __syncthreads();
      for (int i=tid;i<NB;i+=BLOCK){
        float a  = wf[i];
        float nn = (i+1<NB) ? wf[i+1] : 0.f;
        if (a > nn) atomicMin(&s_idx, i);
      }
      __syncthreads();
      bp2 = (s_idx < NB) ? s_idx : 0;
    }
    const float Mab2 = Mab + ((bp2+1<NB) ? wf[bp2+1] : 0.f);
    __syncthreads();
    if (tid < 256){ wf[tid]=0.f; wu[tid]=0u; }
    __syncthreads();
    const uint32_t top24p = (((uint32_t)bp1)<<12) | (uint32_t)bp2;
    ROW4_BEGIN
      if ((u>>8) == top24p){
        bool kk_ok = (!topk_act) || (u > uk) || (u == uk && idx <= idxk);
        if (kk_ok){
          atomicAdd(&wf[u & 0xFFu], expf(x));
          atomicAdd(&wu[u & 0xFFu], 1u);
        }
      }
    ROW4_END
    __syncthreads();
    if (tid==0){
      float run = 0.f; int b3 = -1; float mgt = 0.f;
      for (int i=255;i>=0;--i){
        float sufn = run; run += wf[i];
        if (Mab2 + run > tgt && Mab2 + sufn <= tgt){ b3 = i; mgt = Mab2 + sufn; break; }
      }
      if (b3 < 0){
        float run2 = 0.f;
        for (int i=255;i>=0;--i){
          if (wu[i] > 0u){ b3 = i; mgt = Mab2 + run2; }
          run2 += wf[i];
        }
        if (b3 < 0){ b3 = 0; mgt = Mab2; }
      }
      const uint32_t upv = (((uint32_t)bp1)<<20) | (((uint32_t)bp2)<<8) | (uint32_t)b3;
      const int ntp = (int)wu[b3];
      const float ev = expf(keyval(upv));
      int t = 0;
      for (int j=1;j<=ntp;j++){
        float before = mgt + (float)(j-1) * ev;
        if (before / Zk <= p) t++; else break;
      }
      if (t < 1) t = 1;
      s_up = upv; s_tp = t; s_ntp = ntp; s_n = 0;
    }
    __syncthreads();
    up = s_up;
    if (s_tp < s_ntp){
      ROW4_BEGIN
        if (u == up){
          bool kk_ok = (!topk_act) || (u > uk) || (u == uk && idx <= idxk);
          if (kk_ok){
            int pos = atomicAdd(&s_n, 1);
            if (pos < NB) wu[pos] = idx;
          }
        }
      ROW4_END
      __syncthreads();
      if (tid==0){
        int n2 = min(s_n, NB);
        int t  = min(s_tp, n2);
        s_idxp = select_tth_smallest(wu, n2, t);
      }
      __syncthreads();
      idxp = s_idxp;
    }
  }

  // final: argmax over kept set of (exp(x-m)/Zs)/e
  const float m  = s_m;
  const float Zs = Zk * expf(-m);
  ull best = 0ull;
  ROW4_BEGIN
    bool kk_ok = (!topk_act) || (u > uk) || (u == uk && idx <= idxk);
    bool kp_ok = pall || (u > up) || (u == up && idx <= idxp);
    if (kk_ok && kp_ok){
      float q = (expf(x - m) / Zs) / exp_noise((uint32_t)b * (uint32_t)VV + idx);
      ull pk = (((ull)__float_as_uint(q)) << 32) | (uint32_t)(~idx);
      best = (pk > best) ? pk : best;
    }
  ROW4_END
  red[tid] = best; __syncthreads();
  for (int d=BLOCK/2; d>0; d>>=1){
    if (tid < d){ ull o = red[tid+d]; if (o > red[tid]) red[tid] = o; }
    __syncthreads();
  }
  if (tid==0) out[b] = (int)(~(uint32_t)(red[0] & 0xFFFFFFFFull));
}

extern "C" void kernel_launch(void* const* d_in, const int* in_sizes, int n_in,
                              void* d_out, int out_size, void* d_ws, size_t ws_size,
                              hipStream_t stream) {
  (void)in_sizes; (void)n_in; (void)out_size; (void)d_ws; (void)ws_size;
  const float* logits = (const float*)d_in[0];
  const float* temps  = (const float*)d_in[1];
  const int*   ks     = (const int*)d_in[2];
  const float* ps     = (const float*)d_in[3];
  int* out = (int*)d_out;
  sampler_kernel<<<256, BLOCK, 0, stream>>>(logits, temps, ks, ps, out);
}

// Round 5
// 231.529 us; speedup vs baseline: 2.2922x; 1.0682x over previous
//
#include <hip/hip_runtime.h>
#include <stdint.h>

#define VV 128000
#define BLOCK 1024
#define NB 4096
#define CAP 4096

typedef unsigned long long ull;

__device__ __forceinline__ uint32_t rotl32(uint32_t x, int r){ return (x << r) | (x >> (32 - r)); }

// Bit-exact replica of jax.random.exponential(key(42), (256,128000), f32) at flat
// index f, under jax_threefry_partitionable=True: per element,
// threefry2x32(key, counter=(hi32(i), lo32(i))), bits = out0 ^ out1.
__device__ __forceinline__ float exp_noise(uint32_t f){
  const uint32_t ks0 = 0u, ks1 = 42u, ks2 = 0x1BD11BDAu ^ 0u ^ 42u;
  uint32_t x0 = 0u + ks0;
  uint32_t x1 = f + ks1;
#define R1(r) { x0 += x1; x1 = rotl32(x1, r); x1 ^= x0; }
  R1(13) R1(15) R1(26) R1(6)   x0 += ks1; x1 += ks2 + 1u;
  R1(17) R1(29) R1(16) R1(24)  x0 += ks2; x1 += ks0 + 2u;
  R1(13) R1(15) R1(26) R1(6)   x0 += ks0; x1 += ks1 + 3u;
  R1(17) R1(29) R1(16) R1(24)  x0 += ks1; x1 += ks2 + 4u;
  R1(13) R1(15) R1(26) R1(6)   x0 += ks2; x1 += ks0 + 5u;
#undef R1
  uint32_t bits = x0 ^ x1;
  float u = __uint_as_float((bits >> 9) | 0x3F800000u) - 1.0f;
  float e = -log1pf(-u);
  return fmaxf(e, 1e-10f);
}

// ascending-order key: larger float -> larger key (total order; no NaN in input)
__device__ __forceinline__ uint32_t fkey(float x){
  uint32_t u = __float_as_uint(x);
  return u ^ ((u & 0x80000000u) ? 0xFFFFFFFFu : 0x80000000u);
}
__device__ __forceinline__ float keyval(uint32_t k){
  uint32_t bits = (k & 0x80000000u) ? (k ^ 0x80000000u) : ~k;
  return __uint_as_float(bits);
}

// In-place inclusive suffix sum over NB=4096 entries (4 per thread + Hillis-Steele).
__device__ void suffix_scan_u(uint32_t* h, uint32_t* tmp, int tid){
  const int base = tid * 4;
  uint32_t l0=h[base], l1=h[base+1], l2=h[base+2], l3=h[base+3];
  uint32_t s3=l3, s2=l2+s3, s1=l1+s2, s0=l0+s1;
  tmp[tid] = s0; __syncthreads();
  for (int d=1; d<BLOCK; d<<=1){
    uint32_t add = (tid+d<BLOCK) ? tmp[tid+d] : 0u;
    __syncthreads();
    tmp[tid] += add;
    __syncthreads();
  }
  uint32_t E = (tid+1<BLOCK) ? tmp[tid+1] : 0u;
  h[base]=s0+E; h[base+1]=s1+E; h[base+2]=s2+E; h[base+3]=s3+E;
  __syncthreads();
}
__device__ void suffix_scan_f(float* h, float* tmp, int tid){
  const int base = tid * 4;
  float l0=h[base], l1=h[base+1], l2=h[base+2], l3=h[base+3];
  float s3=l3, s2=l2+s3, s1=l1+s2, s0=l0+s1;
  tmp[tid] = s0; __syncthreads();
  for (int d=1; d<BLOCK; d<<=1){
    float add = (tid+d<BLOCK) ? tmp[tid+d] : 0.f;
    __syncthreads();
    tmp[tid] += add;
    __syncthreads();
  }
  float E = (tid+1<BLOCK) ? tmp[tid+1] : 0.f;
  h[base]=s0+E; h[base+1]=s1+E; h[base+2]=s2+E; h[base+3]=s3+E;
  __syncthreads();
}

// tid0-serial: move the t smallest of a[0..n) to front, return t-th smallest.
__device__ uint32_t select_tth_smallest(uint32_t* a, int n, int t){
  for (int i=0;i<t;i++){
    int mi=i; uint32_t mv=a[i];
    for (int j=i+1;j<n;j++) if (a[j]<mv){ mv=a[j]; mi=j; }
    a[mi]=a[i]; a[i]=mv;
  }
  return a[t-1];
}

// bitonic ascending on packed (~key, idx): value desc, idx asc (stable argsort(-x))
__device__ void bitonic_sort(ull* a, int N, int tid){
  for (int len=2; len<=N; len<<=1){
    for (int j=len>>1; j>0; j>>=1){
      for (int i=tid; i<N; i+=BLOCK){
        int l = i ^ j;
        if (l > i){
          ull x = a[i], y = a[l];
          bool asc = ((i & len) == 0);
          if (asc ? (x > y) : (x < y)){ a[i]=y; a[l]=x; }
        }
      }
      __syncthreads();
    }
  }
}

// Raw-key row loop (no division): u = fkey(raw logit).
#define ROW4R_BEGIN \
    for (int c0 = tid; c0 < VV/4; c0 += BLOCK*4){ \
      float4 qv[4]; int cb[4]; bool gv[4]; \
      _Pragma("unroll") \
      for (int t=0;t<4;t++){ int cc = c0 + t*BLOCK; gv[t] = (cc < VV/4); cb[t] = cc*4; if (gv[t]) qv[t] = rp[cc]; } \
      _Pragma("unroll") \
      for (int t=0;t<4;t++) if (gv[t]){ \
        float vs[4] = {qv[t].x, qv[t].y, qv[t].z, qv[t].w}; \
        _Pragma("unroll") \
        for (int j=0;j<4;j++){ \
          uint32_t u = fkey(vs[j]); \
          uint32_t idx = (uint32_t)(cb[t]+j); \
          (void)idx;
#define ROW4R_END } } }

// x-key row loop (exact x = v/T), for the slow (k==0 / overflow) path.
#define ROW4_BEGIN \
    for (int c0 = tid; c0 < VV/4; c0 += BLOCK*4){ \
      float4 qv[4]; int cb[4]; bool gv[4]; \
      _Pragma("unroll") \
      for (int t=0;t<4;t++){ int cc = c0 + t*BLOCK; gv[t] = (cc < VV/4); cb[t] = cc*4; if (gv[t]) qv[t] = rp[cc]; } \
      _Pragma("unroll") \
      for (int t=0;t<4;t++) if (gv[t]){ \
        float xs[4] = {qv[t].x, qv[t].y, qv[t].z, qv[t].w}; \
        _Pragma("unroll") \
        for (int j=0;j<4;j++){ \
          float x = xs[j]/T; \
          uint32_t u = fkey(x); \
          uint32_t idx = (uint32_t)(cb[t]+j); \
          (void)idx;
#define ROW4_END } } }

__global__ __launch_bounds__(BLOCK) void sampler_kernel(
    const float* __restrict__ logits, const float* __restrict__ temps,
    const int* __restrict__ topks, const float* __restrict__ topps,
    int* __restrict__ out)
{
  // Carved shared memory (102400 B):
  //  [0,64K)   h4 u32[16384] 4-copy hist | later: cand ull[4096] @0 (32K),
  //            h2 u32[4096] @32K (16K), sort2 ull[1024] @48K (8K)
  //            slow path: S f[4096] @0, wf f[4096] @16K
  //  [64K,80K) wu u32[4096]
  //  [80K,84K) tmpf f[1024]; [84K,88K) tmpu u32[1024];
  //  [88K,92K) ck f[1024];   [92K,100K) red ull[1024]
  __shared__ __align__(16) uint8_t SM[102400];
  uint32_t* h4    = (uint32_t*)SM;
  ull*      cand  = (ull*)SM;
  uint32_t* h2    = (uint32_t*)(SM + 32*1024);
  ull*      sort2 = (ull*)(SM + 48*1024);
  float*    S     = (float*)SM;
  float*    wf    = (float*)(SM + 16*1024);
  uint32_t* wu    = (uint32_t*)(SM + 64*1024);
  float*    tmpf  = (float*)(SM + 80*1024);
  uint32_t* tmpu  = (uint32_t*)(SM + 84*1024);
  float*    ck    = (float*)(SM + 88*1024);
  ull*      red   = (ull*)(SM + 92*1024);

  __shared__ int s_idx, s_n, s_n2, s_tk, s_ntk, s_tp, s_ntp;
  __shared__ uint32_t s_uk, s_idxk, s_up, s_idxp;
  __shared__ float s_m, s_Zk, s_Ztot;

  const int b   = blockIdx.x;
  const int tid = threadIdx.x;
  const float T = temps[b];
  const int   k = topks[b];
  const float p = topps[b];
  const float* row = logits + (size_t)b * VV;
  const float4* rp = reinterpret_cast<const float4*>(row);
  const bool topk_act = (k > 0) && (k < VV);
  const bool topp_act = (p > 0.0f) && (p < 1.0f);

  // ============================================================================
  // FAST PATH (k in [1,1023]) — division-free streaming on raw logit keys.
  // Ordering by raw logit == ordering by x=v/T (T>0) up to x-rounding ties.
  // ============================================================================
  if (topk_act){
    for (int i=tid;i<4*NB;i+=BLOCK) h4[i]=0u;
    __syncthreads();
    ROW4R_BEGIN
      atomicAdd(&h4[((u>>20)<<2) | (uint32_t)(tid&3)], 1u);
    ROW4R_END
    __syncthreads();
    for (int i=tid;i<NB;i+=BLOCK)
      wu[i] = h4[(i<<2)] + h4[(i<<2)|1] + h4[(i<<2)|2] + h4[(i<<2)|3];
    __syncthreads();
    suffix_scan_u(wu, tmpu, tid);   // wu[i] = count of items with bucket >= i
    if (tid==0) s_idx = 0;
    __syncthreads();
    for (int i=tid;i<NB;i+=BLOCK){
      uint32_t a  = wu[i];
      uint32_t nn = (i+1<NB) ? wu[i+1] : 0u;
      if (a >= (uint32_t)k && nn < (uint32_t)k) s_idx = i;
    }
    __syncthreads();
    const uint32_t beta = (uint32_t)s_idx;
    const int n = (int)wu[beta];                          // exact, >= k
    const uint32_t c_above = (beta+1<NB) ? wu[beta+1] : 0u; // exact, < k
    if (n <= CAP){
      if (tid==0) s_n = 0;
      __syncthreads();
      ROW4R_BEGIN
        if ((u>>20) >= beta){
          int pos = atomicAdd(&s_n, 1);
          cand[pos] = (((ull)(~u))<<32) | idx;   // pos < n <= CAP guaranteed
        }
      ROW4R_END
      __syncthreads();
      // ---- prune to <=1024 entries before sorting (integer-exact) ----
      ull* srt; int m;
      if (n <= 1024){ srt = cand; m = n; }
      else {
        for (int i=tid;i<NB;i+=BLOCK) h2[i]=0u;
        __syncthreads();
        for (int i=tid;i<n;i+=BLOCK){
          uint32_t u2 = ~(uint32_t)(cand[i]>>32);
          if ((u2>>20) == beta) atomicAdd(&h2[(u2>>8)&0xFFFu], 1u);
        }
        __syncthreads();
        suffix_scan_u(h2, tmpu, tid);
        const uint32_t kr = (uint32_t)k - c_above;   // >= 1
        if (tid==0) s_idx = 0;
        __syncthreads();
        for (int i=tid;i<NB;i+=BLOCK){
          uint32_t a  = h2[i];
          uint32_t nn = (i+1<NB) ? h2[i+1] : 0u;
          if (a >= kr && nn < kr) s_idx = i;
        }
        __syncthreads();
        const uint32_t gam = (uint32_t)s_idx;
        const int np = (int)(c_above + h2[gam]);     // exact survivors, >= k
        if (np <= 1024){
          if (tid==0) s_n2 = 0;
          __syncthreads();
          const uint32_t cut24 = (beta<<12) | gam;
          for (int i=tid;i<n;i+=BLOCK){
            ull e = cand[i];
            uint32_t u2 = ~(uint32_t)(e>>32);
            if ((u2>>8) >= cut24){
              int pos = atomicAdd(&s_n2, 1);
              sort2[pos] = e;                        // pos < np guaranteed
            }
          }
          __syncthreads();
          srt = sort2; m = np;
        } else { srt = cand; m = n; }                // massive sub-bucket tie: rare
      }
      int N = 2; while (N < m) N <<= 1;
      for (int i=tid;i<N;i+=BLOCK) if (i >= m) srt[i] = 0xFFFFFFFFFFFFFFFFull;
      __syncthreads();
      bitonic_sort(srt, N, tid);
      // ---- exact top-k = first k entries; softmax over them ----
      const int kk = k;
      const float xm = keyval(~(uint32_t)(srt[0]>>32)) / T;   // row max of x
      float w = 0.f; uint32_t myidx = 0u;
      if (tid < kk){
        ull e = srt[tid];
        myidx = (uint32_t)e;
        float xv = keyval(~(uint32_t)(e>>32)) / T;
        w = expf(xv - xm);
      }
      ck[tid] = w; __syncthreads();
      for (int d=BLOCK/2; d>0; d>>=1){
        if (tid < d) ck[tid] += ck[tid+d];
        __syncthreads();
      }
      if (tid==0) s_Ztot = ck[0];
      __syncthreads();
      const float Zk = s_Ztot;
      // inclusive cumsum of probs; count cumsum <= p among first kk
      ck[tid] = w / Zk; __syncthreads();
      for (int d=1; d<BLOCK; d<<=1){
        float add = (tid >= d) ? ck[tid-d] : 0.f;
        __syncthreads();
        ck[tid] += add;
        __syncthreads();
      }
      tmpu[tid] = (tid < kk && ck[tid] <= p) ? 1u : 0u;
      __syncthreads();
      for (int d=BLOCK/2; d>0; d>>=1){
        if (tid < d) tmpu[tid] += tmpu[tid+d];
        __syncthreads();
      }
      int L;
      if (!topp_act) L = kk;
      else { int c = (int)tmpu[0]; L = (c >= kk) ? kk : (c + 1); }
      // Gumbel-race argmax over first L: argmax w_i / e_i (scale-invariant)
      ull best = 0ull;
      if (tid < L){
        float q = w / exp_noise((uint32_t)b * (uint32_t)VV + myidx);
        best = (((ull)__float_as_uint(q)) << 32) | (uint32_t)(~myidx);
      }
      red[tid] = best; __syncthreads();
      for (int d=BLOCK/2; d>0; d>>=1){
        if (tid < d){ ull o = red[tid+d]; if (o > red[tid]) red[tid] = o; }
        __syncthreads();
      }
      if (tid==0) out[b] = (int)(~(uint32_t)(red[0] & 0xFFFFFFFFull));
      return;
    }
    __syncthreads();  // n > CAP (statistically never) -> slow path
  }

  // ============================================================================
  // SLOW PATH (k==0, or fast-path overflow): round-3 verified radix machinery
  // ============================================================================
  for (int i=tid;i<NB;i+=BLOCK){ S[i]=0.f; wu[i]=0u; }
  __syncthreads();
  float lmax = -3.4e38f;
  ROW4_BEGIN
    lmax = fmaxf(lmax, x);
    atomicAdd(&wu[u>>20], 1u);
    atomicAdd(&S[u>>20], expf(x));
  ROW4_END
  tmpf[tid] = lmax; __syncthreads();
  for (int d=BLOCK/2; d>0; d>>=1){
    if (tid < d) tmpf[tid] = fmaxf(tmpf[tid], tmpf[tid+d]);
    __syncthreads();
  }
  if (tid==0) s_m = tmpf[0];
  __syncthreads();
  suffix_scan_u(wu, tmpu, tid);
  suffix_scan_f(S,  tmpf, tid);

  uint32_t uk = 0u, idxk = 0xFFFFFFFFu;
  int bk1 = -1;
  if (topk_act){
    if (tid==0) s_idx = 0;
    __syncthreads();
    for (int i=tid;i<NB;i+=BLOCK){
      uint32_t a  = wu[i];
      uint32_t nn = (i+1<NB) ? wu[i+1] : 0u;
      if (a >= (uint32_t)k && nn < (uint32_t)k) s_idx = i;
    }
    __syncthreads();
    bk1 = s_idx;
    const uint32_t c_above1 = (bk1+1<NB) ? wu[bk1+1] : 0u;
    const float    M_above1 = (bk1+1<NB) ? S[bk1+1]  : 0.f;
    __syncthreads();
    for (int i=tid;i<NB;i+=BLOCK){ wu[i]=0u; wf[i]=0.f; }
    __syncthreads();
    ROW4_BEGIN
      if ((int)(u>>20) == bk1){
        atomicAdd(&wu[(u>>8)&0xFFFu], 1u);
        atomicAdd(&wf[(u>>8)&0xFFFu], expf(x));
      }
    ROW4_END
    __syncthreads();
    suffix_scan_u(wu, tmpu, tid);
    suffix_scan_f(wf, tmpf, tid);
    if (tid==0) s_idx = 0;
    __syncthreads();
    for (int i=tid;i<NB;i+=BLOCK){
      uint32_t a  = c_above1 + wu[i];
      uint32_t nn = c_above1 + ((i+1<NB) ? wu[i+1] : 0u);
      if (a >= (uint32_t)k && nn < (uint32_t)k) s_idx = i;
    }
    __syncthreads();
    const int bk2 = s_idx;
    const uint32_t c_above2 = c_above1 + ((bk2+1<NB) ? wu[bk2+1] : 0u);
    const float    M_above2 = M_above1 + ((bk2+1<NB) ? wf[bk2+1] : 0.f);
    __syncthreads();
    if (tid < 256){ wu[tid]=0u; wf[tid]=0.f; }
    __syncthreads();
    const uint32_t top24k = (((uint32_t)bk1)<<12) | (uint32_t)bk2;
    ROW4_BEGIN
      if ((u>>8) == top24k){
        atomicAdd(&wu[u & 0xFFu], 1u);
        atomicAdd(&wf[u & 0xFFu], expf(x));
      }
    ROW4_END
    __syncthreads();
    if (tid==0){
      uint32_t r = 0u; float mr = 0.f; int b3 = 0;
      for (int i=255;i>=0;--i){
        if (c_above2 + r + wu[i] >= (uint32_t)k){ b3 = i; break; }
        r += wu[i]; mr += wf[i];
      }
      const uint32_t cgt = c_above2 + r;
      const float mgt = M_above2 + mr;
      const int nt = (int)wu[b3];
      const int tk = k - (int)cgt;
      s_uk  = (((uint32_t)bk1)<<20) | (((uint32_t)bk2)<<8) | (uint32_t)b3;
      s_tk  = tk; s_ntk = nt;
      s_Zk  = mgt + (float)tk * expf(keyval(s_uk));
      s_n   = 0;
    }
    __syncthreads();
    uk = s_uk;
    if (s_tk < s_ntk){
      ROW4_BEGIN
        if (u == uk){
          int pos = atomicAdd(&s_n, 1);
          if (pos < NB) wu[pos] = idx;
        }
      ROW4_END
      __syncthreads();
      if (tid==0){
        int n2 = min(s_n, NB);
        int t  = min(s_tk, n2);
        s_idxk = select_tth_smallest(wu, n2, t);
      }
      __syncthreads();
      idxk = s_idxk;
    }
  }
  const float Zk = topk_act ? s_Zk : S[0];

  uint32_t up = 0u, idxp = 0xFFFFFFFFu;
  const float tgt = p * Zk;
  const bool pall = (!topp_act) || (tgt >= Zk);
  if (!pall){
    if (tid==0) s_idx = -2;
    __syncthreads();
    for (int i=tid;i<NB;i+=BLOCK){
      if (i > bk1){
        float a  = S[i];
        float nn = (i+1<NB) ? S[i+1] : 0.f;
        if (a > tgt && nn <= tgt) s_idx = i;
      }
    }
    __syncthreads();
    int bp1 = (s_idx >= 0) ? s_idx : bk1;
    if (bp1 < 0) bp1 = 0;
    const float Mab = (bp1+1<NB) ? S[bp1+1] : 0.f;
    __syncthreads();
    for (int i=tid;i<NB;i+=BLOCK) wf[i]=0.f;
    __syncthreads();
    ROW4_BEGIN
      if ((int)(u>>20) == bp1){
        bool kk_ok = (!topk_act) || (u > uk) || (u == uk && idx <= idxk);
        if (kk_ok) atomicAdd(&wf[(u>>8)&0xFFFu], expf(x));
      }
    ROW4_END
    __syncthreads();
    suffix_scan_f(wf, tmpf, tid);
    if (tid==0) s_idx = -2;
    __syncthreads();
    for (int i=tid;i<NB;i+=BLOCK){
      float a  = Mab + wf[i];
      float nn = Mab + ((i+1<NB) ? wf[i+1] : 0.f);
      if (a > tgt && nn <= tgt) s_idx = i;
    }
    __syncthreads();
    int bp2;
    if (s_idx >= 0){ bp2 = s_idx; }
    else {
      if (tid==0) s_idx = NB;
      __syncthreads();
      for (int i=tid;i<NB;i+=BLOCK){
        float a  = wf[i];
        float nn = (i+1<NB) ? wf[i+1] : 0.f;
        if (a > nn) atomicMin(&s_idx, i);
      }
      __syncthreads();
      bp2 = (s_idx < NB) ? s_idx : 0;
    }
    const float Mab2 = Mab + ((bp2+1<NB) ? wf[bp2+1] : 0.f);
    __syncthreads();
    if (tid < 256){ wf[tid]=0.f; wu[tid]=0u; }
    __syncthreads();
    const uint32_t top24p = (((uint32_t)bp1)<<12) | (uint32_t)bp2;
    ROW4_BEGIN
      if ((u>>8) == top24p){
        bool kk_ok = (!topk_act) || (u > uk) || (u == uk && idx <= idxk);
        if (kk_ok){
          atomicAdd(&wf[u & 0xFFu], expf(x));
          atomicAdd(&wu[u & 0xFFu], 1u);
        }
      }
    ROW4_END
    __syncthreads();
    if (tid==0){
      float run = 0.f; int b3 = -1; float mgt = 0.f;
      for (int i=255;i>=0;--i){
        float sufn = run; run += wf[i];
        if (Mab2 + run > tgt && Mab2 + sufn <= tgt){ b3 = i; mgt = Mab2 + sufn; break; }
      }
      if (b3 < 0){
        float run2 = 0.f;
        for (int i=255;i>=0;--i){
          if (wu[i] > 0u){ b3 = i; mgt = Mab2 + run2; }
          run2 += wf[i];
        }
        if (b3 < 0){ b3 = 0; mgt = Mab2; }
      }
      const uint32_t upv = (((uint32_t)bp1)<<20) | (((uint32_t)bp2)<<8) | (uint32_t)b3;
      const int ntp = (int)wu[b3];
      const float ev = expf(keyval(upv));
      int t = 0;
      for (int j=1;j<=ntp;j++){
        float before = mgt + (float)(j-1) * ev;
        if (before / Zk <= p) t++; else break;
      }
      if (t < 1) t = 1;
      s_up = upv; s_tp = t; s_ntp = ntp; s_n = 0;
    }
    __syncthreads();
    up = s_up;
    if (s_tp < s_ntp){
      ROW4_BEGIN
        if (u == up){
          bool kk_ok = (!topk_act) || (u > uk) || (u == uk && idx <= idxk);
          if (kk_ok){
            int pos = atomicAdd(&s_n, 1);
            if (pos < NB) wu[pos] = idx;
          }
        }
      ROW4_END
      __syncthreads();
      if (tid==0){
        int n2 = min(s_n, NB);
        int t  = min(s_tp, n2);
        s_idxp = select_tth_smallest(wu, n2, t);
      }
      __syncthreads();
      idxp = s_idxp;
    }
  }

  const float m  = s_m;
  const float Zs = Zk * expf(-m);
  ull best = 0ull;
  ROW4_BEGIN
    bool kk_ok = (!topk_act) || (u > uk) || (u == uk && idx <= idxk);
    bool kp_ok = pall || (u > up) || (u == up && idx <= idxp);
    if (kk_ok && kp_ok){
      float q = (expf(x - m) / Zs) / exp_noise((uint32_t)b * (uint32_t)VV + idx);
      ull pk = (((ull)__float_as_uint(q)) << 32) | (uint32_t)(~idx);
      best = (pk > best) ? pk : best;
    }
  ROW4_END
  red[tid] = best; __syncthreads();
  for (int d=BLOCK/2; d>0; d>>=1){
    if (tid < d){ ull o = red[tid+d]; if (o > red[tid]) red[tid] = o; }
    __syncthreads();
  }
  if (tid==0) out[b] = (int)(~(uint32_t)(red[0] & 0xFFFFFFFFull));
}

extern "C" void kernel_launch(void* const* d_in, const int* in_sizes, int n_in,
                              void* d_out, int out_size, void* d_ws, size_t ws_size,
                              hipStream_t stream) {
  (void)in_sizes; (void)n_in; (void)out_size; (void)d_ws; (void)ws_size;
  const float* logits = (const float*)d_in[0];
  const float* temps  = (const float*)d_in[1];
  const int*   ks     = (const int*)d_in[2];
  const float* ps     = (const float*)d_in[3];
  int* out = (int*)d_out;
  sampler_kernel<<<256, BLOCK, 0, stream>>>(logits, temps, ks, ps, out);
}